// Round 6
// baseline (179.383 us; speedup 1.0000x reference)
//
#include <hip/hip_runtime.h>

#define BB    256
#define NVERT 10475
#define NKPT  144
#define MVERT 778
#define MKPT  21
#define NBDRY 8192
#define KNB   9
#define ITERS 5
#define NV3   (NVERT * 3)
#define MV3   (MVERT * 3)   // 2334

typedef float f32x4 __attribute__((ext_vector_type(4)));

static __device__ __forceinline__ float bfu(unsigned hi16) {
    return __uint_as_float(hi16);
}
// f32 -> bf16 bits, round-to-nearest-even
static __device__ __forceinline__ unsigned f2bf(float f) {
    unsigned u = __float_as_uint(f);
    u += 0x7FFFu + ((u >> 16) & 1u);
    return u >> 16;
}

// pack one float (global dword position p within the batch slice) into the
// bf16 mesh: vertex = p/3, component = p%3, stored as ushort at v*4+c.
static __device__ __forceinline__ void pack_one(unsigned short* msh16, unsigned p, float val) {
    unsigned v = p / 3u;
    unsigned c = p - v * 3u;
    msh16[v * 4u + c] = (unsigned short)f2bf(val);
}

// dense f32x4 copy global -> LDS staging
static __device__ __forceinline__ void stage_load(const float* __restrict__ g,
                                                  float* sh, int n, int t, int nt) {
    unsigned lead = (4u - ((unsigned)(((size_t)g) >> 2) & 3u)) & 3u;
    unsigned nb4 = ((unsigned)n - lead) >> 2;
    if (t == 0) for (unsigned e = 0; e < lead; ++e) sh[e] = g[e];
    if (t == 1) for (unsigned e = lead + 4u * nb4; e < (unsigned)n; ++e) sh[e] = g[e];
    const f32x4* g4 = (const f32x4*)(g + lead);
    for (unsigned i4 = (unsigned)t; i4 < nb4; i4 += (unsigned)nt) {
        f32x4 q = g4[i4];
        unsigned p = lead + 4u * i4;
        sh[p] = q.x; sh[p + 1] = q.y; sh[p + 2] = q.z; sh[p + 3] = q.w;
    }
}

// ---------------------------------------------------------------------------
// Per (batch, hand) rigid alignment. f32; Jacobi fully unrolled (registers).
// ---------------------------------------------------------------------------
static __device__ void compute_align(
    int b, int h,
    const float* __restrict__ skpt, const float* __restrict__ rkpt,
    const float* __restrict__ lkpt, const float* __restrict__ rpose,
    const float* __restrict__ lpose, const int* __restrict__ perm,
    const int* __restrict__ ralign, const int* __restrict__ lalign,
    float* o)
{
    const float* pose = (h ? lpose : rpose) + b * 3;
    const float* kpt  = (h ? lkpt : rkpt) + (size_t)b * MKPT * 3;
    const int* alidx  = h ? lalign : ralign;

    float ax = pose[0], ay = pose[1], az = pose[2];
    float ang = sqrtf(ax*ax + ay*ay + az*az);
    float ia = 1.0f / (ang + 1e-8f);
    float x = ax*ia, y = ay*ia, z = az*ia;
    float c = cosf(ang), s = sinf(ang), Cc = 1.0f - c;
    float A00 = c + x*x*Cc,   A01 = x*y*Cc - z*s, A02 = x*z*Cc + y*s;
    float A10 = y*x*Cc + z*s, A11 = c + y*y*Cc,   A12 = y*z*Cc - x*s;
    float A20 = z*x*Cc - y*s, A21 = z*y*Cc + x*s, A22 = c + z*z*Cc;

    float sX0=0,sX1=0,sX2=0, sY0=0,sY1=0,sY2=0;
    float S00=0,S01=0,S02=0,S10=0,S11=0,S12=0,S20=0,S21=0,S22=0;
    for (int n = 0; n < MKPT; ++n) {
        int pi = perm[n];
        float p0 = kpt[pi*3+0], p1 = kpt[pi*3+1], p2 = kpt[pi*3+2];
        float X0 = A00*p0 + A10*p1 + A20*p2;
        float X1 = A01*p0 + A11*p1 + A21*p2;
        float X2 = A02*p0 + A12*p1 + A22*p2;
        int qi = alidx[n];
        const float* yp = skpt + ((size_t)b * NKPT + qi) * 3;
        float Y0 = yp[0], Y1 = yp[1], Y2 = yp[2];
        sX0 += X0; sX1 += X1; sX2 += X2;
        sY0 += Y0; sY1 += Y1; sY2 += Y2;
        S00 += X0*Y0; S01 += X0*Y1; S02 += X0*Y2;
        S10 += X1*Y0; S11 += X1*Y1; S12 += X1*Y2;
        S20 += X2*Y0; S21 += X2*Y1; S22 += X2*Y2;
    }
    const float invN = 1.0f / (float)MKPT;
    float C00 = S00 - sX0*sY0*invN, C01 = S01 - sX0*sY1*invN, C02 = S02 - sX0*sY2*invN;
    float C10 = S10 - sX1*sY0*invN, C11 = S11 - sX1*sY1*invN, C12 = S12 - sX1*sY2*invN;
    float C20 = S20 - sX2*sY0*invN, C21 = S21 - sX2*sY1*invN, C22 = S22 - sX2*sY2*invN;

    float N[4][4];
    N[0][0] = C00 + C11 + C22;
    N[0][1] = C21 - C12; N[0][2] = C02 - C20; N[0][3] = C10 - C01;
    N[1][1] = C00 - C11 - C22; N[1][2] = C01 + C10; N[1][3] = C02 + C20;
    N[2][2] = -C00 + C11 - C22; N[2][3] = C12 + C21;
    N[3][3] = -C00 - C11 + C22;
    N[1][0] = N[0][1]; N[2][0] = N[0][2]; N[3][0] = N[0][3];
    N[2][1] = N[1][2]; N[3][1] = N[1][3]; N[3][2] = N[2][3];

    float V[4][4] = {{1,0,0,0},{0,1,0,0},{0,0,1,0},{0,0,0,1}};
    for (int sweep = 0; sweep < 10; ++sweep) {
        float off = N[0][1]*N[0][1] + N[0][2]*N[0][2] + N[0][3]*N[0][3]
                  + N[1][2]*N[1][2] + N[1][3]*N[1][3] + N[2][3]*N[2][3];
        if (off < 1e-14f) break;
        #pragma unroll
        for (int p = 0; p < 3; ++p) {
            #pragma unroll
            for (int q = p + 1; q < 4; ++q) {
                float apq = N[p][q];
                if (fabsf(apq) > 1e-30f) {
                    float theta = (N[q][q] - N[p][p]) / (2.0f * apq);
                    float tt = copysignf(1.0f, theta) / (fabsf(theta) + sqrtf(theta*theta + 1.0f));
                    float cj = rsqrtf(tt*tt + 1.0f);
                    float sj = tt * cj;
                    #pragma unroll
                    for (int k = 0; k < 4; ++k) {
                        float akp = N[k][p], akq = N[k][q];
                        N[k][p] = cj*akp - sj*akq;
                        N[k][q] = sj*akp + cj*akq;
                    }
                    #pragma unroll
                    for (int k = 0; k < 4; ++k) {
                        float apk = N[p][k], aqk = N[q][k];
                        N[p][k] = cj*apk - sj*aqk;
                        N[q][k] = sj*apk + cj*aqk;
                    }
                    #pragma unroll
                    for (int k = 0; k < 4; ++k) {
                        float vkp = V[k][p], vkq = V[k][q];
                        V[k][p] = cj*vkp - sj*vkq;
                        V[k][q] = sj*vkp + cj*vkq;
                    }
                }
            }
        }
    }
    int m = 0;
    float lmax = N[0][0];
    if (N[1][1] > lmax) { lmax = N[1][1]; m = 1; }
    if (N[2][2] > lmax) { lmax = N[2][2]; m = 2; }
    if (N[3][3] > lmax) { lmax = N[3][3]; m = 3; }
    float w = V[0][m], qx = V[1][m], qy = V[2][m], qz = V[3][m];

    float R00 = 1.0f - 2.0f*(qy*qy + qz*qz), R01 = 2.0f*(qx*qy - w*qz), R02 = 2.0f*(qx*qz + w*qy);
    float R10 = 2.0f*(qx*qy + w*qz), R11 = 1.0f - 2.0f*(qx*qx + qz*qz), R12 = 2.0f*(qy*qz - w*qx);
    float R20 = 2.0f*(qx*qz - w*qy), R21 = 2.0f*(qy*qz + w*qx), R22 = 1.0f - 2.0f*(qx*qx + qy*qy);

    float mX0 = sX0*invN, mX1 = sX1*invN, mX2 = sX2*invN;
    float mY0 = sY0*invN, mY1 = sY1*invN, mY2 = sY2*invN;

    o[0]  = A00*R00 + A01*R10 + A02*R20;
    o[1]  = A00*R01 + A01*R11 + A02*R21;
    o[2]  = A00*R02 + A01*R12 + A02*R22;
    o[3]  = A10*R00 + A11*R10 + A12*R20;
    o[4]  = A10*R01 + A11*R11 + A12*R21;
    o[5]  = A10*R02 + A11*R12 + A12*R22;
    o[6]  = A20*R00 + A21*R10 + A22*R20;
    o[7]  = A20*R01 + A21*R11 + A22*R21;
    o[8]  = A20*R02 + A21*R12 + A22*R22;
    o[9]  = mY0 - (mX0*R00 + mX1*R10 + mX2*R20);
    o[10] = mY1 - (mX0*R01 + mX1*R11 + mX2*R21);
    o[11] = mY2 - (mX0*R02 + mX1*R12 + mX2*R22);
}

// ---------------------------------------------------------------------------
// Single fused kernel: one workgroup (1024 thr) per batch.
// __launch_bounds__(1024, 4): 16 waves/CU = 4 waves/EU -> 128 VGPR budget,
// enough for the full per-thread record state (no scratch spill).
// ---------------------------------------------------------------------------
__global__ __launch_bounds__(1024, 4) void fused_kernel(
    const float* __restrict__ svert,  // [B, NVERT, 3]
    const float* __restrict__ skpt,   // [B, NKPT, 3]
    const float* __restrict__ rv,     // [B, MVERT, 3]
    const float* __restrict__ rpose,  // [B, 3]
    const float* __restrict__ lv,
    const float* __restrict__ lkpt_unused,
    const float* __restrict__ lkpt,
    const float* __restrict__ lpose,
    const int*   __restrict__ perm,   // [MKPT]
    const int*   __restrict__ ralign, // [MKPT]
    const int*   __restrict__ lalign,
    const int*   __restrict__ ridx,   // [MVERT]
    const int*   __restrict__ lidx,
    const int*   __restrict__ bidx,   // [NBDRY]
    const int*   __restrict__ vnbr,   // [NVERT, KNB]
    const float* __restrict__ rkpt,   // [B, MKPT, 3]
    float*       __restrict__ out)    // [B, NVERT, 3]
{
    __shared__ __align__(16) unsigned short msh16[(NVERT + 1) * 4];  // 83.8 KB
    __shared__ __align__(16) float hstage[2 * MV3];                  // 18.7 KB
    __shared__ unsigned char flag[NVERT];                            // 10.5 KB
    __shared__ float affsh[24];
    const int b = blockIdx.x;
    const int tid = threadIdx.x;

    // ---- phase A: zero flags, dummy slot, pack neighbor records (8/thread) --
    for (int i = tid; i < NVERT; i += 1024) flag[i] = 0;
    if (tid == 0) *((uint2*)(msh16 + NVERT * 4)) = make_uint2(0u, 0u);

    unsigned w0[8], w1[8], w2[8], w3[8], w4[8];
    float invk[8];
    #pragma unroll
    for (int k = 0; k < 8; ++k) {
        int j = k * 1024 + tid;
        int bi = bidx[j];
        const int* row = vnbr + (size_t)bi * KNB;
        unsigned n[9]; int cnt = 0;
        #pragma unroll
        for (int e = 0; e < 9; ++e) {
            int vv = row[e];
            if (vv >= 0) { n[e] = (unsigned)vv; ++cnt; }
            else         { n[e] = (unsigned)NVERT; }
        }
        if (cnt == 0) cnt = 1;
        w0[k] = n[0] | (n[1] << 14);
        w1[k] = n[2] | (n[3] << 14);
        w2[k] = n[4] | (n[5] << 14);
        w3[k] = n[6] | (n[7] << 14);
        w4[k] = n[8] | ((unsigned)bi << 14);
        invk[k] = 1.0f / (float)cnt;
    }
    __syncthreads();   // flags zeroed

    // ---- phase B: align (lanes 0,1) || flag-set + staging (tid>=64) ----
    if (tid < 2) {
        compute_align(b, tid, skpt, rkpt, lkpt, rpose, lpose,
                      perm, ralign, lalign, affsh + tid * 12);
    } else if (tid >= 64) {
        const int t = tid - 64;
        for (int j = t; j < NBDRY; j += 960) flag[bidx[j]] = 1;
        const float* g = svert + (size_t)b * NV3;
        unsigned lead = (4u - ((unsigned)(((size_t)g) >> 2) & 3u)) & 3u;
        unsigned nb4 = ((unsigned)NV3 - lead) >> 2;
        if (t == 0) for (unsigned e = 0; e < lead; ++e) pack_one(msh16, e, g[e]);
        if (t == 1) for (unsigned e = lead + 4u * nb4; e < (unsigned)NV3; ++e) pack_one(msh16, e, g[e]);
        const f32x4* g4 = (const f32x4*)(g + lead);
        for (unsigned i4 = (unsigned)t; i4 < nb4; i4 += 960u) {
            f32x4 q = g4[i4];
            unsigned p = lead + 4u * i4;
            pack_one(msh16, p,     q.x);
            pack_one(msh16, p + 1, q.y);
            pack_one(msh16, p + 2, q.z);
            pack_one(msh16, p + 3, q.w);
        }
        stage_load(rv + (size_t)b * MV3, hstage,       MV3, t, 960);
        stage_load(lv + (size_t)b * MV3, hstage + MV3, MV3, t, 960);
    }
    __syncthreads();   // flags set, mesh+hands staged, affines ready

    // ---- phase C: transform + scatter hand verts ----
    for (int i = tid; i < 2 * MVERT; i += 1024) {
        int h = (i >= MVERT) ? 1 : 0;
        int nn = i - h * MVERT;
        const int* hidx = h ? lidx : ridx;
        const float* M = affsh + h * 12;
        const float* p = hstage + h * MV3 + nn * 3;
        float p0 = p[0], p1 = p[1], p2 = p[2];
        float o0 = p0 * M[0] + p1 * M[3] + p2 * M[6] + M[9];
        float o1 = p0 * M[1] + p1 * M[4] + p2 * M[7] + M[10];
        float o2 = p0 * M[2] + p1 * M[5] + p2 * M[8] + M[11];
        ((uint2*)msh16)[hidx[nn]] = make_uint2(f2bf(o0) | (f2bf(o1) << 16), f2bf(o2));
    }
    __syncthreads();

    const uint2* mesh = (const uint2*)msh16;

    // ---- phase D-init: current value, static-neighbor base, dummy-subst ----
    float cx[8], cy[8], cz[8], bx[8], by[8], bz[8];
    #pragma unroll
    for (int k = 0; k < 8; ++k) {
        int bi = (int)((w4[k] >> 14) & 0x3FFFu);
        uint2 m = mesh[bi];
        cx[k] = bfu(m.x << 16);
        cy[k] = bfu(m.x & 0xFFFF0000u);
        cz[k] = bfu(m.y << 16);
        // static mask: valid neighbor that is NOT a boundary vertex
        unsigned s = 0;
#define CHK(BIT, IDXEXPR) { unsigned gi = (IDXEXPR); \
        if (gi != (unsigned)NVERT && !flag[gi]) s |= (BIT); }
        CHK(1u,   w0[k] & 0x3FFFu)
        CHK(2u,   (w0[k] >> 14) & 0x3FFFu)
        CHK(4u,   w1[k] & 0x3FFFu)
        CHK(8u,   (w1[k] >> 14) & 0x3FFFu)
        CHK(16u,  w2[k] & 0x3FFFu)
        CHK(32u,  (w2[k] >> 14) & 0x3FFFu)
        CHK(64u,  w3[k] & 0x3FFFu)
        CHK(128u, (w3[k] >> 14) & 0x3FFFu)
        CHK(256u, w4[k] & 0x3FFFu)
#undef CHK
        float tx = 0.f, ty = 0.f, tz = 0.f;
#define STATG(BIT, IDXEXPR) { unsigned gi = (s & (BIT)) ? (IDXEXPR) : (unsigned)NVERT; \
        uint2 mm = mesh[gi]; \
        tx += bfu(mm.x << 16); ty += bfu(mm.x & 0xFFFF0000u); tz += bfu(mm.y << 16); }
        STATG(1u,   w0[k] & 0x3FFFu)
        STATG(2u,   (w0[k] >> 14) & 0x3FFFu)
        STATG(4u,   w1[k] & 0x3FFFu)
        STATG(8u,   (w1[k] >> 14) & 0x3FFFu)
        STATG(16u,  w2[k] & 0x3FFFu)
        STATG(32u,  (w2[k] >> 14) & 0x3FFFu)
        STATG(64u,  w3[k] & 0x3FFFu)
        STATG(128u, (w3[k] >> 14) & 0x3FFFu)
        STATG(256u, w4[k] & 0x3FFFu)
#undef STATG
        bx[k] = tx; by[k] = ty; bz[k] = tz;
        // replace static slots with dummy so iter-loop gathers broadcast
        const unsigned LOW = 0x3FFFu, HIGH = 0x3FFFu << 14;
        const unsigned DLO = (unsigned)NVERT, DHI = ((unsigned)NVERT) << 14;
        w0[k] = (s & 1u)   ? ((w0[k] & ~LOW)  | DLO) : w0[k];
        w0[k] = (s & 2u)   ? ((w0[k] & ~HIGH) | DHI) : w0[k];
        w1[k] = (s & 4u)   ? ((w1[k] & ~LOW)  | DLO) : w1[k];
        w1[k] = (s & 8u)   ? ((w1[k] & ~HIGH) | DHI) : w1[k];
        w2[k] = (s & 16u)  ? ((w2[k] & ~LOW)  | DLO) : w2[k];
        w2[k] = (s & 32u)  ? ((w2[k] & ~HIGH) | DHI) : w2[k];
        w3[k] = (s & 64u)  ? ((w3[k] & ~LOW)  | DLO) : w3[k];
        w3[k] = (s & 128u) ? ((w3[k] & ~HIGH) | DHI) : w3[k];
        w4[k] = (s & 256u) ? ((w4[k] & ~LOW)  | DLO) : w4[k];
    }

    // ---- phase D: 5 Jacobi smoothing iterations ----
#define NB_GATHER(idx) { uint2 m = mesh[(idx)]; \
        sx += bfu(m.x << 16); sy += bfu(m.x & 0xFFFF0000u); sz += bfu(m.y << 16); }
    for (int itr = 0; itr < ITERS; ++itr) {
        #pragma unroll
        for (int k = 0; k < 8; ++k) {
            float sx = 0.f, sy = 0.f, sz = 0.f;
            NB_GATHER(w0[k] & 0x3FFFu);
            NB_GATHER((w0[k] >> 14) & 0x3FFFu);
            NB_GATHER(w1[k] & 0x3FFFu);
            NB_GATHER((w1[k] >> 14) & 0x3FFFu);
            NB_GATHER(w2[k] & 0x3FFFu);
            NB_GATHER((w2[k] >> 14) & 0x3FFFu);
            NB_GATHER(w3[k] & 0x3FFFu);
            NB_GATHER((w3[k] >> 14) & 0x3FFFu);
            NB_GATHER(w4[k] & 0x3FFFu);
            cx[k] = 0.5f * cx[k] + 0.5f * (sx + bx[k]) * invk[k];
            cy[k] = 0.5f * cy[k] + 0.5f * (sy + by[k]) * invk[k];
            cz[k] = 0.5f * cz[k] + 0.5f * (sz + bz[k]) * invk[k];
        }
        __syncthreads();
        #pragma unroll
        for (int k = 0; k < 8; ++k) {
            int bi = (int)((w4[k] >> 14) & 0x3FFFu);
            ((uint2*)msh16)[bi] = make_uint2(f2bf(cx[k]) | (f2bf(cy[k]) << 16), f2bf(cz[k]));
        }
        __syncthreads();
    }
#undef NB_GATHER

    // ---- phase E: write back, dense aligned f32x4 ----
    float* dst = out + (size_t)b * NV3;
    const unsigned lead = (4u - ((unsigned)(((size_t)dst) >> 2) & 3u)) & 3u;
#define COMP(i, val) { unsigned v_ = (i) / 3u; unsigned c_ = (i) - v_ * 3u; \
        uint2 m_ = mesh[v_]; \
        val = (c_ == 0u) ? bfu(m_.x << 16) : (c_ == 1u) ? bfu(m_.x & 0xFFFF0000u) : bfu(m_.y << 16); }
    if ((unsigned)tid < lead) {
        float v; COMP((unsigned)tid, v);
        dst[tid] = v;
    }
    const unsigned nb4 = ((unsigned)NV3 - lead) >> 2;
    f32x4* dst4 = (f32x4*)(dst + lead);
    for (unsigned i4 = (unsigned)tid; i4 < nb4; i4 += 1024u) {
        unsigned i0 = lead + 4u * i4;
        f32x4 o;
        COMP(i0 + 0u, o.x);
        COMP(i0 + 1u, o.y);
        COMP(i0 + 2u, o.z);
        COMP(i0 + 3u, o.w);
        dst4[i4] = o;
    }
    const unsigned done = lead + 4u * nb4;
    if ((unsigned)tid < (unsigned)NV3 - done) {
        float v; COMP(done + (unsigned)tid, v);
        dst[done + tid] = v;
    }
#undef COMP
}

extern "C" void kernel_launch(void* const* d_in, const int* in_sizes, int n_in,
                              void* d_out, int out_size, void* d_ws, size_t ws_size,
                              hipStream_t stream) {
    const float* svert  = (const float*)d_in[0];
    const float* skpt   = (const float*)d_in[1];
    const float* rv     = (const float*)d_in[2];
    const float* rk     = (const float*)d_in[3];
    const float* rpose  = (const float*)d_in[4];
    const float* lv     = (const float*)d_in[5];
    const float* lk     = (const float*)d_in[6];
    const float* lpose  = (const float*)d_in[7];
    const int*   perm   = (const int*)d_in[8];
    const int*   ralign = (const int*)d_in[9];
    const int*   lalign = (const int*)d_in[10];
    const int*   ridx   = (const int*)d_in[11];
    const int*   lidx   = (const int*)d_in[12];
    const int*   bidx   = (const int*)d_in[15];
    const int*   vnbr   = (const int*)d_in[16];
    float* out = (float*)d_out;

    fused_kernel<<<BB, 1024, 0, stream>>>(svert, skpt, rv, rpose,
                                          lv, nullptr, lk, lpose,
                                          perm, ralign, lalign,
                                          ridx, lidx, bidx, vnbr, rk, out);
}

// Round 7
// 68.834 us; speedup vs baseline: 2.6060x; 2.6060x over previous
//
#include <hip/hip_runtime.h>

#define BB    256
#define NVERT 10475
#define NKPT  144
#define MVERT 778
#define MKPT  21
#define NBDRY 8192
#define KNB   9
#define ITERS 5
#define NV3   (NVERT * 3)
#define MV3   (MVERT * 3)   // 2334

typedef float f32x4 __attribute__((ext_vector_type(4)));

static __device__ __forceinline__ float bfu(unsigned hi16) {
    return __uint_as_float(hi16);
}
// f32 -> bf16 bits, round-to-nearest-even
static __device__ __forceinline__ unsigned f2bf(float f) {
    unsigned u = __float_as_uint(f);
    u += 0x7FFFu + ((u >> 16) & 1u);
    return u >> 16;
}

// pack one float (global dword position p within the batch slice) into the
// bf16 mesh: vertex = p/3, component = p%3, stored as ushort at v*4+c.
static __device__ __forceinline__ void pack_one(unsigned short* msh16, unsigned p, float val) {
    unsigned v = p / 3u;
    unsigned c = p - v * 3u;
    msh16[v * 4u + c] = (unsigned short)f2bf(val);
}

// dense f32x4 copy global -> LDS staging
static __device__ __forceinline__ void stage_load(const float* __restrict__ g,
                                                  float* sh, int n, int t, int nt) {
    unsigned lead = (4u - ((unsigned)(((size_t)g) >> 2) & 3u)) & 3u;
    unsigned nb4 = ((unsigned)n - lead) >> 2;
    if (t == 0) for (unsigned e = 0; e < lead; ++e) sh[e] = g[e];
    if (t == 1) for (unsigned e = lead + 4u * nb4; e < (unsigned)n; ++e) sh[e] = g[e];
    const f32x4* g4 = (const f32x4*)(g + lead);
    for (unsigned i4 = (unsigned)t; i4 < nb4; i4 += (unsigned)nt) {
        f32x4 q = g4[i4];
        unsigned p = lead + 4u * i4;
        sh[p] = q.x; sh[p + 1] = q.y; sh[p + 2] = q.z; sh[p + 3] = q.w;
    }
}

// ---------------------------------------------------------------------------
// Per (batch, hand) rigid alignment. f32; Jacobi fully unrolled (registers).
// ---------------------------------------------------------------------------
static __device__ void compute_align(
    int b, int h,
    const float* __restrict__ skpt, const float* __restrict__ rkpt,
    const float* __restrict__ lkpt, const float* __restrict__ rpose,
    const float* __restrict__ lpose, const int* __restrict__ perm,
    const int* __restrict__ ralign, const int* __restrict__ lalign,
    float* o)
{
    const float* pose = (h ? lpose : rpose) + b * 3;
    const float* kpt  = (h ? lkpt : rkpt) + (size_t)b * MKPT * 3;
    const int* alidx  = h ? lalign : ralign;

    float ax = pose[0], ay = pose[1], az = pose[2];
    float ang = sqrtf(ax*ax + ay*ay + az*az);
    float ia = 1.0f / (ang + 1e-8f);
    float x = ax*ia, y = ay*ia, z = az*ia;
    float c = cosf(ang), s = sinf(ang), Cc = 1.0f - c;
    float A00 = c + x*x*Cc,   A01 = x*y*Cc - z*s, A02 = x*z*Cc + y*s;
    float A10 = y*x*Cc + z*s, A11 = c + y*y*Cc,   A12 = y*z*Cc - x*s;
    float A20 = z*x*Cc - y*s, A21 = z*y*Cc + x*s, A22 = c + z*z*Cc;

    float sX0=0,sX1=0,sX2=0, sY0=0,sY1=0,sY2=0;
    float S00=0,S01=0,S02=0,S10=0,S11=0,S12=0,S20=0,S21=0,S22=0;
    for (int n = 0; n < MKPT; ++n) {
        int pi = perm[n];
        float p0 = kpt[pi*3+0], p1 = kpt[pi*3+1], p2 = kpt[pi*3+2];
        float X0 = A00*p0 + A10*p1 + A20*p2;
        float X1 = A01*p0 + A11*p1 + A21*p2;
        float X2 = A02*p0 + A12*p1 + A22*p2;
        int qi = alidx[n];
        const float* yp = skpt + ((size_t)b * NKPT + qi) * 3;
        float Y0 = yp[0], Y1 = yp[1], Y2 = yp[2];
        sX0 += X0; sX1 += X1; sX2 += X2;
        sY0 += Y0; sY1 += Y1; sY2 += Y2;
        S00 += X0*Y0; S01 += X0*Y1; S02 += X0*Y2;
        S10 += X1*Y0; S11 += X1*Y1; S12 += X1*Y2;
        S20 += X2*Y0; S21 += X2*Y1; S22 += X2*Y2;
    }
    const float invN = 1.0f / (float)MKPT;
    float C00 = S00 - sX0*sY0*invN, C01 = S01 - sX0*sY1*invN, C02 = S02 - sX0*sY2*invN;
    float C10 = S10 - sX1*sY0*invN, C11 = S11 - sX1*sY1*invN, C12 = S12 - sX1*sY2*invN;
    float C20 = S20 - sX2*sY0*invN, C21 = S21 - sX2*sY1*invN, C22 = S22 - sX2*sY2*invN;

    float N[4][4];
    N[0][0] = C00 + C11 + C22;
    N[0][1] = C21 - C12; N[0][2] = C02 - C20; N[0][3] = C10 - C01;
    N[1][1] = C00 - C11 - C22; N[1][2] = C01 + C10; N[1][3] = C02 + C20;
    N[2][2] = -C00 + C11 - C22; N[2][3] = C12 + C21;
    N[3][3] = -C00 - C11 + C22;
    N[1][0] = N[0][1]; N[2][0] = N[0][2]; N[3][0] = N[0][3];
    N[2][1] = N[1][2]; N[3][1] = N[1][3]; N[3][2] = N[2][3];

    float V[4][4] = {{1,0,0,0},{0,1,0,0},{0,0,1,0},{0,0,0,1}};
    for (int sweep = 0; sweep < 10; ++sweep) {
        float off = N[0][1]*N[0][1] + N[0][2]*N[0][2] + N[0][3]*N[0][3]
                  + N[1][2]*N[1][2] + N[1][3]*N[1][3] + N[2][3]*N[2][3];
        if (off < 1e-12f) break;
        #pragma unroll
        for (int p = 0; p < 3; ++p) {
            #pragma unroll
            for (int q = p + 1; q < 4; ++q) {
                float apq = N[p][q];
                if (fabsf(apq) > 1e-30f) {
                    float theta = (N[q][q] - N[p][p]) / (2.0f * apq);
                    float tt = copysignf(1.0f, theta) / (fabsf(theta) + sqrtf(theta*theta + 1.0f));
                    float cj = rsqrtf(tt*tt + 1.0f);
                    float sj = tt * cj;
                    #pragma unroll
                    for (int k = 0; k < 4; ++k) {
                        float akp = N[k][p], akq = N[k][q];
                        N[k][p] = cj*akp - sj*akq;
                        N[k][q] = sj*akp + cj*akq;
                    }
                    #pragma unroll
                    for (int k = 0; k < 4; ++k) {
                        float apk = N[p][k], aqk = N[q][k];
                        N[p][k] = cj*apk - sj*aqk;
                        N[q][k] = sj*apk + cj*aqk;
                    }
                    #pragma unroll
                    for (int k = 0; k < 4; ++k) {
                        float vkp = V[k][p], vkq = V[k][q];
                        V[k][p] = cj*vkp - sj*vkq;
                        V[k][q] = sj*vkp + cj*vkq;
                    }
                }
            }
        }
    }
    int m = 0;
    float lmax = N[0][0];
    if (N[1][1] > lmax) { lmax = N[1][1]; m = 1; }
    if (N[2][2] > lmax) { lmax = N[2][2]; m = 2; }
    if (N[3][3] > lmax) { lmax = N[3][3]; m = 3; }
    float w = V[0][m], qx = V[1][m], qy = V[2][m], qz = V[3][m];

    float R00 = 1.0f - 2.0f*(qy*qy + qz*qz), R01 = 2.0f*(qx*qy - w*qz), R02 = 2.0f*(qx*qz + w*qy);
    float R10 = 2.0f*(qx*qy + w*qz), R11 = 1.0f - 2.0f*(qx*qx + qz*qz), R12 = 2.0f*(qy*qz - w*qx);
    float R20 = 2.0f*(qx*qz - w*qy), R21 = 2.0f*(qy*qz + w*qx), R22 = 1.0f - 2.0f*(qx*qx + qy*qy);

    float mX0 = sX0*invN, mX1 = sX1*invN, mX2 = sX2*invN;
    float mY0 = sY0*invN, mY1 = sY1*invN, mY2 = sY2*invN;

    o[0]  = A00*R00 + A01*R10 + A02*R20;
    o[1]  = A00*R01 + A01*R11 + A02*R21;
    o[2]  = A00*R02 + A01*R12 + A02*R22;
    o[3]  = A10*R00 + A11*R10 + A12*R20;
    o[4]  = A10*R01 + A11*R11 + A12*R21;
    o[5]  = A10*R02 + A11*R12 + A12*R22;
    o[6]  = A20*R00 + A21*R10 + A22*R20;
    o[7]  = A20*R01 + A21*R11 + A22*R21;
    o[8]  = A20*R02 + A21*R12 + A22*R22;
    o[9]  = mY0 - (mX0*R00 + mX1*R10 + mX2*R20);
    o[10] = mY1 - (mX0*R01 + mX1*R11 + mX2*R21);
    o[11] = mY2 - (mX0*R02 + mX1*R12 + mX2*R22);
}

// ---------------------------------------------------------------------------
// Single fused kernel: one workgroup (1024 thr) per batch.
// Per-thread state kept <= ~60 VGPRs (w0..w4[8]=40 + uint2 up[8]=16) so the
// 64-VGPR allocation holds everything: NO scratch spill (the round-5/6 FETCH/
// WRITE blowup was spill traffic). Self value and counts are re-derived per
// iteration (1 extra LDS gather + v_rcp) instead of living in registers.
// ---------------------------------------------------------------------------
__global__ __launch_bounds__(1024, 1) void fused_kernel(
    const float* __restrict__ svert,  // [B, NVERT, 3]
    const float* __restrict__ skpt,   // [B, NKPT, 3]
    const float* __restrict__ rv,     // [B, MVERT, 3]
    const float* __restrict__ rkpt,   // [B, MKPT, 3]
    const float* __restrict__ rpose,  // [B, 3]
    const float* __restrict__ lv,
    const float* __restrict__ lkpt,
    const float* __restrict__ lpose,
    const int*   __restrict__ perm,   // [MKPT]
    const int*   __restrict__ ralign, // [MKPT]
    const int*   __restrict__ lalign,
    const int*   __restrict__ ridx,   // [MVERT]
    const int*   __restrict__ lidx,
    const int*   __restrict__ bidx,   // [NBDRY]
    const int*   __restrict__ vnbr,   // [NVERT, KNB]
    float*       __restrict__ out)    // [B, NVERT, 3]
{
    __shared__ __align__(16) unsigned short msh16[(NVERT + 1) * 4];  // 83.8 KB
    __shared__ __align__(16) float hstage[2 * MV3];                  // 18.7 KB
    __shared__ float affsh[24];
    const int b = blockIdx.x;
    const int tid = threadIdx.x;

    // ---- phase A: align (lanes 0,1) || staging (tid>=64); record pack (all) --
    if (tid < 2) {
        compute_align(b, tid, skpt, rkpt, lkpt, rpose, lpose,
                      perm, ralign, lalign, affsh + tid * 12);
    } else if (tid == 2) {
        *((uint2*)(msh16 + NVERT * 4)) = make_uint2(0u, 0u);  // dummy slot
    } else if (tid >= 64) {
        const int t = tid - 64;
        const float* g = svert + (size_t)b * NV3;
        unsigned lead = (4u - ((unsigned)(((size_t)g) >> 2) & 3u)) & 3u;
        unsigned nb4 = ((unsigned)NV3 - lead) >> 2;
        if (t == 0) for (unsigned e = 0; e < lead; ++e) pack_one(msh16, e, g[e]);
        if (t == 1) for (unsigned e = lead + 4u * nb4; e < (unsigned)NV3; ++e) pack_one(msh16, e, g[e]);
        const f32x4* g4 = (const f32x4*)(g + lead);
        for (unsigned i4 = (unsigned)t; i4 < nb4; i4 += 960u) {
            f32x4 q = g4[i4];
            unsigned p = lead + 4u * i4;
            pack_one(msh16, p,     q.x);
            pack_one(msh16, p + 1, q.y);
            pack_one(msh16, p + 2, q.z);
            pack_one(msh16, p + 3, q.w);
        }
        stage_load(rv + (size_t)b * MV3, hstage,       MV3, t, 960);
        stage_load(lv + (size_t)b * MV3, hstage + MV3, MV3, t, 960);
    }

    // record pack (all threads, 8/thread), overlapped with the above:
    // w0..w3: neighbor idx pairs (14b, invalid -> NVERT dummy)
    // w4: n8 | bi<<14 | cnt<<28
    unsigned w0[8], w1[8], w2[8], w3[8], w4[8];
    #pragma unroll
    for (int k = 0; k < 8; ++k) {
        int j = k * 1024 + tid;
        int bi = bidx[j];
        const int* row = vnbr + (size_t)bi * KNB;
        unsigned n[9]; unsigned cnt = 0;
        #pragma unroll
        for (int e = 0; e < 9; ++e) {
            int vv = row[e];
            if (vv >= 0) { n[e] = (unsigned)vv; ++cnt; }
            else         { n[e] = (unsigned)NVERT; }
        }
        if (cnt == 0) cnt = 1;
        w0[k] = n[0] | (n[1] << 14);
        w1[k] = n[2] | (n[3] << 14);
        w2[k] = n[4] | (n[5] << 14);
        w3[k] = n[6] | (n[7] << 14);
        w4[k] = n[8] | ((unsigned)bi << 14) | (cnt << 28);
    }
    __syncthreads();   // mesh+hands staged, affines ready

    // ---- phase B: transform + scatter hand verts ----
    for (int i = tid; i < 2 * MVERT; i += 1024) {
        int h = (i >= MVERT) ? 1 : 0;
        int nn = i - h * MVERT;
        const int* hidx = h ? lidx : ridx;
        const float* M = affsh + h * 12;
        const float* p = hstage + h * MV3 + nn * 3;
        float p0 = p[0], p1 = p[1], p2 = p[2];
        float o0 = p0 * M[0] + p1 * M[3] + p2 * M[6] + M[9];
        float o1 = p0 * M[1] + p1 * M[4] + p2 * M[7] + M[10];
        float o2 = p0 * M[2] + p1 * M[5] + p2 * M[8] + M[11];
        ((uint2*)msh16)[hidx[nn]] = make_uint2(f2bf(o0) | (f2bf(o1) << 16), f2bf(o2));
    }
    __syncthreads();

    const uint2* mesh = (const uint2*)msh16;

    // ---- phase C: 5 Jacobi smoothing iterations (self re-gathered) ----
#define NB_GATHER(idx) { uint2 m = mesh[(idx)]; \
        sx += bfu(m.x << 16); sy += bfu(m.x & 0xFFFF0000u); sz += bfu(m.y << 16); }
    for (int itr = 0; itr < ITERS; ++itr) {
        uint2 up[8];
        #pragma unroll
        for (int k = 0; k < 8; ++k) {
            float sx = 0.f, sy = 0.f, sz = 0.f;
            NB_GATHER(w0[k] & 0x3FFFu);
            NB_GATHER((w0[k] >> 14) & 0x3FFFu);
            NB_GATHER(w1[k] & 0x3FFFu);
            NB_GATHER((w1[k] >> 14) & 0x3FFFu);
            NB_GATHER(w2[k] & 0x3FFFu);
            NB_GATHER((w2[k] >> 14) & 0x3FFFu);
            NB_GATHER(w3[k] & 0x3FFFu);
            NB_GATHER((w3[k] >> 14) & 0x3FFFu);
            NB_GATHER(w4[k] & 0x3FFFu);
            uint2 ms = mesh[(w4[k] >> 14) & 0x3FFFu];   // self
            float hinv = 0.5f * __builtin_amdgcn_rcpf((float)(w4[k] >> 28));
            float ux = 0.5f * bfu(ms.x << 16)         + hinv * sx;
            float uy = 0.5f * bfu(ms.x & 0xFFFF0000u) + hinv * sy;
            float uz = 0.5f * bfu(ms.y << 16)         + hinv * sz;
            up[k] = make_uint2(f2bf(ux) | (f2bf(uy) << 16), f2bf(uz));
        }
        __syncthreads();
        #pragma unroll
        for (int k = 0; k < 8; ++k) {
            ((uint2*)msh16)[(w4[k] >> 14) & 0x3FFFu] = up[k];
        }
        __syncthreads();
    }
#undef NB_GATHER

    // ---- phase D: write back, dense aligned f32x4 ----
    float* dst = out + (size_t)b * NV3;
    const unsigned lead = (4u - ((unsigned)(((size_t)dst) >> 2) & 3u)) & 3u;
#define COMP(i, val) { unsigned v_ = (i) / 3u; unsigned c_ = (i) - v_ * 3u; \
        uint2 m_ = mesh[v_]; \
        val = (c_ == 0u) ? bfu(m_.x << 16) : (c_ == 1u) ? bfu(m_.x & 0xFFFF0000u) : bfu(m_.y << 16); }
    if ((unsigned)tid < lead) {
        float v; COMP((unsigned)tid, v);
        dst[tid] = v;
    }
    const unsigned nb4 = ((unsigned)NV3 - lead) >> 2;
    f32x4* dst4 = (f32x4*)(dst + lead);
    for (unsigned i4 = (unsigned)tid; i4 < nb4; i4 += 1024u) {
        unsigned i0 = lead + 4u * i4;
        f32x4 o;
        COMP(i0 + 0u, o.x);
        COMP(i0 + 1u, o.y);
        COMP(i0 + 2u, o.z);
        COMP(i0 + 3u, o.w);
        dst4[i4] = o;
    }
    const unsigned done = lead + 4u * nb4;
    if ((unsigned)tid < (unsigned)NV3 - done) {
        float v; COMP(done + (unsigned)tid, v);
        dst[done + tid] = v;
    }
#undef COMP
}

extern "C" void kernel_launch(void* const* d_in, const int* in_sizes, int n_in,
                              void* d_out, int out_size, void* d_ws, size_t ws_size,
                              hipStream_t stream) {
    const float* svert  = (const float*)d_in[0];
    const float* skpt   = (const float*)d_in[1];
    const float* rv     = (const float*)d_in[2];
    const float* rk     = (const float*)d_in[3];
    const float* rpose  = (const float*)d_in[4];
    const float* lv     = (const float*)d_in[5];
    const float* lk     = (const float*)d_in[6];
    const float* lpose  = (const float*)d_in[7];
    const int*   perm   = (const int*)d_in[8];
    const int*   ralign = (const int*)d_in[9];
    const int*   lalign = (const int*)d_in[10];
    const int*   ridx   = (const int*)d_in[11];
    const int*   lidx   = (const int*)d_in[12];
    const int*   bidx   = (const int*)d_in[15];
    const int*   vnbr   = (const int*)d_in[16];
    float* out = (float*)d_out;

    fused_kernel<<<BB, 1024, 0, stream>>>(svert, skpt, rv, rk, rpose,
                                          lv, lk, lpose, perm, ralign, lalign,
                                          ridx, lidx, bidx, vnbr, out);
}

// Round 8
// 64.171 us; speedup vs baseline: 2.7954x; 1.0727x over previous
//
#include <hip/hip_runtime.h>

#define BB    256
#define NVERT 10475
#define NKPT  144
#define MVERT 778
#define MKPT  21
#define NBDRY 8192
#define KNB   9
#define ITERS 5
#define NV3   (NVERT * 3)
#define MV3   (MVERT * 3)   // 2334

typedef float f32x4 __attribute__((ext_vector_type(4)));

static __device__ __forceinline__ float bfu(unsigned hi16) {
    return __uint_as_float(hi16);
}
// f32 -> bf16 bits, round-to-nearest-even
static __device__ __forceinline__ unsigned f2bf(float f) {
    unsigned u = __float_as_uint(f);
    u += 0x7FFFu + ((u >> 16) & 1u);
    return u >> 16;
}

// pack one float (global dword position p within the batch slice) into the
// bf16 mesh: vertex = p/3, component = p%3, stored as ushort at v*4+c.
static __device__ __forceinline__ void pack_one(unsigned short* msh16, unsigned p, float val) {
    unsigned v = p / 3u;
    unsigned c = p - v * 3u;
    msh16[v * 4u + c] = (unsigned short)f2bf(val);
}

// dense f32x4 copy global -> LDS staging
static __device__ __forceinline__ void stage_load(const float* __restrict__ g,
                                                  float* sh, int n, int t, int nt) {
    unsigned lead = (4u - ((unsigned)(((size_t)g) >> 2) & 3u)) & 3u;
    unsigned nb4 = ((unsigned)n - lead) >> 2;
    if (t == 0) for (unsigned e = 0; e < lead; ++e) sh[e] = g[e];
    if (t == 1) for (unsigned e = lead + 4u * nb4; e < (unsigned)n; ++e) sh[e] = g[e];
    const f32x4* g4 = (const f32x4*)(g + lead);
    for (unsigned i4 = (unsigned)t; i4 < nb4; i4 += (unsigned)nt) {
        f32x4 q = g4[i4];
        unsigned p = lead + 4u * i4;
        sh[p] = q.x; sh[p + 1] = q.y; sh[p + 2] = q.z; sh[p + 3] = q.w;
    }
}

// ---------------------------------------------------------------------------
// Per (batch, hand) rigid alignment. f32; Jacobi fully unrolled (registers).
// ---------------------------------------------------------------------------
static __device__ void compute_align(
    int b, int h,
    const float* __restrict__ skpt, const float* __restrict__ rkpt,
    const float* __restrict__ lkpt, const float* __restrict__ rpose,
    const float* __restrict__ lpose, const int* __restrict__ perm,
    const int* __restrict__ ralign, const int* __restrict__ lalign,
    float* o)
{
    const float* pose = (h ? lpose : rpose) + b * 3;
    const float* kpt  = (h ? lkpt : rkpt) + (size_t)b * MKPT * 3;
    const int* alidx  = h ? lalign : ralign;

    float ax = pose[0], ay = pose[1], az = pose[2];
    float ang = sqrtf(ax*ax + ay*ay + az*az);
    float ia = 1.0f / (ang + 1e-8f);
    float x = ax*ia, y = ay*ia, z = az*ia;
    float c = cosf(ang), s = sinf(ang), Cc = 1.0f - c;
    float A00 = c + x*x*Cc,   A01 = x*y*Cc - z*s, A02 = x*z*Cc + y*s;
    float A10 = y*x*Cc + z*s, A11 = c + y*y*Cc,   A12 = y*z*Cc - x*s;
    float A20 = z*x*Cc - y*s, A21 = z*y*Cc + x*s, A22 = c + z*z*Cc;

    float sX0=0,sX1=0,sX2=0, sY0=0,sY1=0,sY2=0;
    float S00=0,S01=0,S02=0,S10=0,S11=0,S12=0,S20=0,S21=0,S22=0;
    for (int n = 0; n < MKPT; ++n) {
        int pi = perm[n];
        float p0 = kpt[pi*3+0], p1 = kpt[pi*3+1], p2 = kpt[pi*3+2];
        float X0 = A00*p0 + A10*p1 + A20*p2;
        float X1 = A01*p0 + A11*p1 + A21*p2;
        float X2 = A02*p0 + A12*p1 + A22*p2;
        int qi = alidx[n];
        const float* yp = skpt + ((size_t)b * NKPT + qi) * 3;
        float Y0 = yp[0], Y1 = yp[1], Y2 = yp[2];
        sX0 += X0; sX1 += X1; sX2 += X2;
        sY0 += Y0; sY1 += Y1; sY2 += Y2;
        S00 += X0*Y0; S01 += X0*Y1; S02 += X0*Y2;
        S10 += X1*Y0; S11 += X1*Y1; S12 += X1*Y2;
        S20 += X2*Y0; S21 += X2*Y1; S22 += X2*Y2;
    }
    const float invN = 1.0f / (float)MKPT;
    float C00 = S00 - sX0*sY0*invN, C01 = S01 - sX0*sY1*invN, C02 = S02 - sX0*sY2*invN;
    float C10 = S10 - sX1*sY0*invN, C11 = S11 - sX1*sY1*invN, C12 = S12 - sX1*sY2*invN;
    float C20 = S20 - sX2*sY0*invN, C21 = S21 - sX2*sY1*invN, C22 = S22 - sX2*sY2*invN;

    float N[4][4];
    N[0][0] = C00 + C11 + C22;
    N[0][1] = C21 - C12; N[0][2] = C02 - C20; N[0][3] = C10 - C01;
    N[1][1] = C00 - C11 - C22; N[1][2] = C01 + C10; N[1][3] = C02 + C20;
    N[2][2] = -C00 + C11 - C22; N[2][3] = C12 + C21;
    N[3][3] = -C00 - C11 + C22;
    N[1][0] = N[0][1]; N[2][0] = N[0][2]; N[3][0] = N[0][3];
    N[2][1] = N[1][2]; N[3][1] = N[1][3]; N[3][2] = N[2][3];

    float V[4][4] = {{1,0,0,0},{0,1,0,0},{0,0,1,0},{0,0,0,1}};
    for (int sweep = 0; sweep < 10; ++sweep) {
        float off = N[0][1]*N[0][1] + N[0][2]*N[0][2] + N[0][3]*N[0][3]
                  + N[1][2]*N[1][2] + N[1][3]*N[1][3] + N[2][3]*N[2][3];
        if (off < 1e-12f) break;
        #pragma unroll
        for (int p = 0; p < 3; ++p) {
            #pragma unroll
            for (int q = p + 1; q < 4; ++q) {
                float apq = N[p][q];
                if (fabsf(apq) > 1e-30f) {
                    float theta = (N[q][q] - N[p][p]) / (2.0f * apq);
                    float tt = copysignf(1.0f, theta) / (fabsf(theta) + sqrtf(theta*theta + 1.0f));
                    float cj = rsqrtf(tt*tt + 1.0f);
                    float sj = tt * cj;
                    #pragma unroll
                    for (int k = 0; k < 4; ++k) {
                        float akp = N[k][p], akq = N[k][q];
                        N[k][p] = cj*akp - sj*akq;
                        N[k][q] = sj*akp + cj*akq;
                    }
                    #pragma unroll
                    for (int k = 0; k < 4; ++k) {
                        float apk = N[p][k], aqk = N[q][k];
                        N[p][k] = cj*apk - sj*aqk;
                        N[q][k] = sj*apk + cj*aqk;
                    }
                    #pragma unroll
                    for (int k = 0; k < 4; ++k) {
                        float vkp = V[k][p], vkq = V[k][q];
                        V[k][p] = cj*vkp - sj*vkq;
                        V[k][q] = sj*vkp + cj*vkq;
                    }
                }
            }
        }
    }
    int m = 0;
    float lmax = N[0][0];
    if (N[1][1] > lmax) { lmax = N[1][1]; m = 1; }
    if (N[2][2] > lmax) { lmax = N[2][2]; m = 2; }
    if (N[3][3] > lmax) { lmax = N[3][3]; m = 3; }
    float w = V[0][m], qx = V[1][m], qy = V[2][m], qz = V[3][m];

    float R00 = 1.0f - 2.0f*(qy*qy + qz*qz), R01 = 2.0f*(qx*qy - w*qz), R02 = 2.0f*(qx*qz + w*qy);
    float R10 = 2.0f*(qx*qy + w*qz), R11 = 1.0f - 2.0f*(qx*qx + qz*qz), R12 = 2.0f*(qy*qz - w*qx);
    float R20 = 2.0f*(qx*qz - w*qy), R21 = 2.0f*(qy*qz + w*qx), R22 = 1.0f - 2.0f*(qx*qx + qy*qy);

    float mX0 = sX0*invN, mX1 = sX1*invN, mX2 = sX2*invN;
    float mY0 = sY0*invN, mY1 = sY1*invN, mY2 = sY2*invN;

    o[0]  = A00*R00 + A01*R10 + A02*R20;
    o[1]  = A00*R01 + A01*R11 + A02*R21;
    o[2]  = A00*R02 + A01*R12 + A02*R22;
    o[3]  = A10*R00 + A11*R10 + A12*R20;
    o[4]  = A10*R01 + A11*R11 + A12*R21;
    o[5]  = A10*R02 + A11*R12 + A12*R22;
    o[6]  = A20*R00 + A21*R10 + A22*R20;
    o[7]  = A20*R01 + A21*R11 + A22*R21;
    o[8]  = A20*R02 + A21*R12 + A22*R22;
    o[9]  = mY0 - (mX0*R00 + mX1*R10 + mX2*R20);
    o[10] = mY1 - (mX0*R01 + mX1*R11 + mX2*R21);
    o[11] = mY2 - (mX0*R02 + mX1*R12 + mX2*R22);
}

// ---------------------------------------------------------------------------
// Setup kernel, WIDE (68 blocks x 128 thr): batch-independent work done once.
//  blocks 0-3 : the 512 (batch, hand) affines -> aff[512*12]
//  blocks 4-67: pack 128 records each into 5-stream SoA table tab[5][NBDRY]
//    (w4 = n8 | bi<<14 | cnt<<28). The random vnbr-row gathers (the address-
//    divergent loads that cost ~30us/block when done inside the main kernel)
//    are paid once here, spread over 64 CUs.
// ---------------------------------------------------------------------------
__global__ __launch_bounds__(128) void setup_kernel(
    const float* __restrict__ skpt, const float* __restrict__ rkpt,
    const float* __restrict__ lkpt, const float* __restrict__ rpose,
    const float* __restrict__ lpose, const int* __restrict__ perm,
    const int* __restrict__ ralign, const int* __restrict__ lalign,
    const int* __restrict__ bidx, const int* __restrict__ vnbr,
    float* __restrict__ aff, unsigned* __restrict__ tab)
{
    const int g = blockIdx.x;
    if (g < 4) {
        int t = g * 128 + threadIdx.x;   // 0..511
        compute_align(t >> 1, t & 1, skpt, rkpt, lkpt, rpose, lpose,
                      perm, ralign, lalign, aff + t * 12);
        return;
    }
    int j = (g - 4) * 128 + threadIdx.x; // 0..8191
    int bi = bidx[j];
    const int* row = vnbr + (size_t)bi * KNB;
    unsigned n[9]; unsigned cnt = 0;
    #pragma unroll
    for (int e = 0; e < 9; ++e) {
        int vv = row[e];
        if (vv >= 0) { n[e] = (unsigned)vv; ++cnt; }
        else         { n[e] = (unsigned)NVERT; }
    }
    if (cnt == 0) cnt = 1;
    tab[0 * NBDRY + j] = n[0] | (n[1] << 14);
    tab[1 * NBDRY + j] = n[2] | (n[3] << 14);
    tab[2 * NBDRY + j] = n[4] | (n[5] << 14);
    tab[3 * NBDRY + j] = n[6] | (n[7] << 14);
    tab[4 * NBDRY + j] = n[8] | ((unsigned)bi << 14) | (cnt << 28);
}

// ---------------------------------------------------------------------------
// Main fused kernel: one workgroup (1024 thr) per batch. Per-thread state
// <= ~56 VGPRs (w0..w4[8]=40 + up[8]=16): spill-free at the 64-VGPR alloc.
// Self value lives in up[] across iterations (9 LDS gathers/record, not 10).
// ---------------------------------------------------------------------------
__global__ __launch_bounds__(1024, 1) void fused_kernel(
    const float* __restrict__ svert,  // [B, NVERT, 3]
    const float* __restrict__ rv,     // [B, MVERT, 3]
    const float* __restrict__ lv,
    const int*   __restrict__ ridx,   // [MVERT]
    const int*   __restrict__ lidx,
    const float* __restrict__ aff,    // [B*2, 12]
    const unsigned* __restrict__ tab, // [5, NBDRY]
    float*       __restrict__ out)    // [B, NVERT, 3]
{
    __shared__ __align__(16) unsigned short msh16[(NVERT + 1) * 4];  // 83.8 KB
    __shared__ __align__(16) float hstage[2 * MV3];                  // 18.7 KB
    __shared__ float affsh[24];
    const int b = blockIdx.x;
    const int tid = threadIdx.x;

    // ---- phase A: staging (all threads) + coalesced table reads ----
    if (tid == 0) *((uint2*)(msh16 + NVERT * 4)) = make_uint2(0u, 0u);
    if (tid < 24) affsh[tid] = aff[b * 24 + tid];
    {
        const float* g = svert + (size_t)b * NV3;
        unsigned lead = (4u - ((unsigned)(((size_t)g) >> 2) & 3u)) & 3u;
        unsigned nb4 = ((unsigned)NV3 - lead) >> 2;
        if (tid == 0) for (unsigned e = 0; e < lead; ++e) pack_one(msh16, e, g[e]);
        if (tid == 1) for (unsigned e = lead + 4u * nb4; e < (unsigned)NV3; ++e) pack_one(msh16, e, g[e]);
        const f32x4* g4 = (const f32x4*)(g + lead);
        for (unsigned i4 = (unsigned)tid; i4 < nb4; i4 += 1024u) {
            f32x4 q = g4[i4];
            unsigned p = lead + 4u * i4;
            pack_one(msh16, p,     q.x);
            pack_one(msh16, p + 1, q.y);
            pack_one(msh16, p + 2, q.z);
            pack_one(msh16, p + 3, q.w);
        }
        stage_load(rv + (size_t)b * MV3, hstage,       MV3, tid, 1024);
        stage_load(lv + (size_t)b * MV3, hstage + MV3, MV3, tid, 1024);
    }
    unsigned w0[8], w1[8], w2[8], w3[8], w4[8];
    #pragma unroll
    for (int k = 0; k < 8; ++k) {
        int j = k * 1024 + tid;
        w0[k] = tab[j];
        w1[k] = tab[NBDRY + j];
        w2[k] = tab[2 * NBDRY + j];
        w3[k] = tab[3 * NBDRY + j];
        w4[k] = tab[4 * NBDRY + j];
    }
    __syncthreads();   // mesh+hands staged, affines visible

    // ---- phase B: transform + scatter hand verts ----
    for (int i = tid; i < 2 * MVERT; i += 1024) {
        int h = (i >= MVERT) ? 1 : 0;
        int nn = i - h * MVERT;
        const int* hidx = h ? lidx : ridx;
        const float* M = affsh + h * 12;
        const float* p = hstage + h * MV3 + nn * 3;
        float p0 = p[0], p1 = p[1], p2 = p[2];
        float o0 = p0 * M[0] + p1 * M[3] + p2 * M[6] + M[9];
        float o1 = p0 * M[1] + p1 * M[4] + p2 * M[7] + M[10];
        float o2 = p0 * M[2] + p1 * M[5] + p2 * M[8] + M[11];
        ((uint2*)msh16)[hidx[nn]] = make_uint2(f2bf(o0) | (f2bf(o1) << 16), f2bf(o2));
    }
    __syncthreads();

    const uint2* mesh = (const uint2*)msh16;

    // self values -> registers (post-scatter), kept across iterations
    uint2 up[8];
    #pragma unroll
    for (int k = 0; k < 8; ++k) up[k] = mesh[(w4[k] >> 14) & 0x3FFFu];

    // ---- phase C: 5 Jacobi smoothing iterations ----
#define NB_GATHER(idx) { uint2 m = mesh[(idx)]; \
        sx += bfu(m.x << 16); sy += bfu(m.x & 0xFFFF0000u); sz += bfu(m.y << 16); }
    for (int itr = 0; itr < ITERS; ++itr) {
        #pragma unroll
        for (int k = 0; k < 8; ++k) {
            float sx = 0.f, sy = 0.f, sz = 0.f;
            NB_GATHER(w0[k] & 0x3FFFu);
            NB_GATHER((w0[k] >> 14) & 0x3FFFu);
            NB_GATHER(w1[k] & 0x3FFFu);
            NB_GATHER((w1[k] >> 14) & 0x3FFFu);
            NB_GATHER(w2[k] & 0x3FFFu);
            NB_GATHER((w2[k] >> 14) & 0x3FFFu);
            NB_GATHER(w3[k] & 0x3FFFu);
            NB_GATHER((w3[k] >> 14) & 0x3FFFu);
            NB_GATHER(w4[k] & 0x3FFFu);
            float hinv = 0.5f * __builtin_amdgcn_rcpf((float)(w4[k] >> 28));
            float ux = 0.5f * bfu(up[k].x << 16)         + hinv * sx;
            float uy = 0.5f * bfu(up[k].x & 0xFFFF0000u) + hinv * sy;
            float uz = 0.5f * bfu(up[k].y << 16)         + hinv * sz;
            up[k] = make_uint2(f2bf(ux) | (f2bf(uy) << 16), f2bf(uz));
        }
        __syncthreads();
        #pragma unroll
        for (int k = 0; k < 8; ++k) {
            ((uint2*)msh16)[(w4[k] >> 14) & 0x3FFFu] = up[k];
        }
        __syncthreads();
    }
#undef NB_GATHER

    // ---- phase D: write back, dense aligned f32x4 ----
    float* dst = out + (size_t)b * NV3;
    const unsigned lead = (4u - ((unsigned)(((size_t)dst) >> 2) & 3u)) & 3u;
#define COMP(i, val) { unsigned v_ = (i) / 3u; unsigned c_ = (i) - v_ * 3u; \
        uint2 m_ = mesh[v_]; \
        val = (c_ == 0u) ? bfu(m_.x << 16) : (c_ == 1u) ? bfu(m_.x & 0xFFFF0000u) : bfu(m_.y << 16); }
    if ((unsigned)tid < lead) {
        float v; COMP((unsigned)tid, v);
        dst[tid] = v;
    }
    const unsigned nb4 = ((unsigned)NV3 - lead) >> 2;
    f32x4* dst4 = (f32x4*)(dst + lead);
    for (unsigned i4 = (unsigned)tid; i4 < nb4; i4 += 1024u) {
        unsigned i0 = lead + 4u * i4;
        f32x4 o;
        COMP(i0 + 0u, o.x);
        COMP(i0 + 1u, o.y);
        COMP(i0 + 2u, o.z);
        COMP(i0 + 3u, o.w);
        dst4[i4] = o;
    }
    const unsigned done = lead + 4u * nb4;
    if ((unsigned)tid < (unsigned)NV3 - done) {
        float v; COMP(done + (unsigned)tid, v);
        dst[done + tid] = v;
    }
#undef COMP
}

extern "C" void kernel_launch(void* const* d_in, const int* in_sizes, int n_in,
                              void* d_out, int out_size, void* d_ws, size_t ws_size,
                              hipStream_t stream) {
    const float* svert  = (const float*)d_in[0];
    const float* skpt   = (const float*)d_in[1];
    const float* rv     = (const float*)d_in[2];
    const float* rk     = (const float*)d_in[3];
    const float* rpose  = (const float*)d_in[4];
    const float* lv     = (const float*)d_in[5];
    const float* lk     = (const float*)d_in[6];
    const float* lpose  = (const float*)d_in[7];
    const int*   perm   = (const int*)d_in[8];
    const int*   ralign = (const int*)d_in[9];
    const int*   lalign = (const int*)d_in[10];
    const int*   ridx   = (const int*)d_in[11];
    const int*   lidx   = (const int*)d_in[12];
    const int*   bidx   = (const int*)d_in[15];
    const int*   vnbr   = (const int*)d_in[16];
    float* out = (float*)d_out;

    float*    aff = (float*)d_ws;                       // 512*12 f32 = 24 KB
    unsigned* tab = (unsigned*)((char*)d_ws + 24576);   // 5*8192 u32 = 160 KB

    setup_kernel<<<68, 128, 0, stream>>>(skpt, rk, lk, rpose, lpose,
                                         perm, ralign, lalign, bidx, vnbr,
                                         aff, tab);
    fused_kernel<<<BB, 1024, 0, stream>>>(svert, rv, lv, ridx, lidx,
                                          aff, tab, out);
}